// Round 12
// baseline (120.936 us; speedup 1.0000x reference)
//
#include <hip/hip_runtime.h>
#include <hip/hip_bf16.h>

#define BATCH 4096
#define IN_DIM 3072
#define HID 1024
#define NSTEP 6

typedef __attribute__((ext_vector_type(8))) short short8;
typedef __attribute__((ext_vector_type(4))) float f32x4;
typedef __attribute__((ext_vector_type(4))) unsigned short ushort4v;

__device__ __forceinline__ void gload_lds16(const void* g, void* lds) {
  __builtin_amdgcn_global_load_lds(
      (const __attribute__((address_space(1))) void*)g,
      (__attribute__((address_space(3))) void*)lds, 16, 0, 0);
}

__device__ __forceinline__ unsigned short f32_to_bf16(float f) {
  unsigned int u = __builtin_bit_cast(unsigned int, f);
  unsigned int r = u + 0x7fffu + ((u >> 16) & 1u);
  return (unsigned short)(r >> 16);
}

// BK=32 granule swizzle (measured round 11: residual 2-way aliasing only,
// ~0.1% of cycles — effectively free).
__device__ __forceinline__ int swz4(int r) { return (r & 3) ^ ((r >> 2) & 3); }

// f32 -> bf16 conversion of We, Wd only (x is staged in-GEMM now)
__global__ void cvt2_kernel(const float* __restrict__ a,
                            const float* __restrict__ b,
                            unsigned short* __restrict__ da,
                            unsigned short* __restrict__ db, int na, int nb) {
  const int total = na + nb;
  const int stride = gridDim.x * blockDim.x;
  for (int i = blockIdx.x * blockDim.x + threadIdx.x; i < total; i += stride) {
    const float* s;
    unsigned short* d;
    int j = i;
    if (j < na) {
      s = a; d = da;
    } else {
      s = b; d = db; j -= na;
    }
    const float4 v = reinterpret_cast<const float4*>(s)[j];
    ushort4v o;
    o.x = f32_to_bf16(v.x);
    o.y = f32_to_bf16(v.y);
    o.z = f32_to_bf16(v.z);
    o.w = f32_to_bf16(v.w);
    reinterpret_cast<ushort4v*>(d)[j] = o;
  }
}

// Split-K2 reduce (p0+p1+bias) + RK4 nmODE. Writes y f32 (NT) + bf16.
__global__ __launch_bounds__(256) void ode_kernel(
    const float* __restrict__ p0, const float* __restrict__ p1,
    const float* __restrict__ be, float* __restrict__ hid,
    unsigned short* __restrict__ hb, int n4) {
  const float dt = 1.0f / (float)NSTEP;
  const float h2 = 0.5f * dt, hd = dt, h6 = dt / 6.0f;
  int stride = gridDim.x * blockDim.x;
  for (int i = blockIdx.x * blockDim.x + threadIdx.x; i < n4; i += stride) {
    const float4 a4 = reinterpret_cast<const float4*>(p0)[i];
    const float4 b4 = reinterpret_cast<const float4*>(p1)[i];
    const float4 e4 = reinterpret_cast<const float4*>(be)[i & (HID / 4 - 1)];
    float g[4] = {a4.x + b4.x + e4.x, a4.y + b4.y + e4.y,
                  a4.z + b4.z + e4.z, a4.w + b4.w + e4.w};
    float y[4] = {0.0f, 0.0f, 0.0f, 0.0f};
#pragma unroll 1
    for (int s = 0; s < NSTEP; ++s) {
      float k1[4], k2[4], k3[4], k4[4];
#pragma unroll
      for (int e = 0; e < 4; ++e) {
        float t = __sinf(y[e] + g[e]);
        k1[e] = t * t - y[e];
      }
#pragma unroll
      for (int e = 0; e < 4; ++e) {
        float yy = fmaf(h2, k1[e], y[e]);
        float t = __sinf(yy + g[e]);
        k2[e] = t * t - yy;
      }
#pragma unroll
      for (int e = 0; e < 4; ++e) {
        float yy = fmaf(h2, k2[e], y[e]);
        float t = __sinf(yy + g[e]);
        k3[e] = t * t - yy;
      }
#pragma unroll
      for (int e = 0; e < 4; ++e) {
        float yy = fmaf(hd, k3[e], y[e]);
        float t = __sinf(yy + g[e]);
        k4[e] = t * t - yy;
      }
#pragma unroll
      for (int e = 0; e < 4; ++e) {
        float ks = k1[e] + 2.0f * (k2[e] + k3[e]) + k4[e];
        y[e] = fmaf(h6, ks, y[e]);
      }
    }
    f32x4 o4;
    o4[0] = y[0]; o4[1] = y[1]; o4[2] = y[2]; o4[3] = y[3];
    __builtin_nontemporal_store(o4, &reinterpret_cast<f32x4*>(hid)[i]);
    ushort4v ob;
    ob.x = f32_to_bf16(y[0]);
    ob.y = f32_to_bf16(y[1]);
    ob.z = f32_to_bf16(y[2]);
    ob.w = f32_to_bf16(y[3]);
    reinterpret_cast<ushort4v*>(hb)[i] = ob;
  }
}

// GEMM1: partials of x(f32) @ We^T. 128x128, BK=32, 4 waves (2x2), split-K=2
// -> 512 blocks. A staged from f32 via registers (issue-early / cvt+ds_write
// -late, T14): saves the 75MB x-conversion round-trip. B staged via
// gload_lds (pre-converted weights). Single __syncthreads per K-step,
// compiler-managed waitcnts (race-free by construction). Swizzled LDS
// (written directly on the A side; rule #21 inverse-source on the B side).
// f32 partial at Cout + sk*BATCH*HID, coalesced.
__global__ __launch_bounds__(256) void gemm1r(
    const float* __restrict__ X, const unsigned short* __restrict__ B,
    float* __restrict__ Cout) {
  constexpr int BM = 128, BN = 128, BK = 32;
  constexpr int Kstride = IN_DIM;    // 3072
  constexpr int Klen = Kstride / 2;  // 1536
  constexpr int ntT = Klen / BK;     // 48
  constexpr int nbn = HID / BN;      // 8
  constexpr int nbm = BATCH / BM;    // 32

  __shared__ unsigned short As[2][BM * BK];
  __shared__ unsigned short Bs[2][BN * BK];

  const int tid = threadIdx.x;
  const int wave = tid >> 6;
  const int lane = tid & 63;
  const int wrow = wave >> 1, wcol = wave & 1;

  const int nwg = gridDim.x;  // 512
  const int swz = (blockIdx.x & 7) * (nwg >> 3) + (blockIdx.x >> 3);
  const int tiles = nbm * nbn;  // 256
  const int sk = swz / tiles;
  const int rem = swz % tiles;
  const int bn = rem % nbn;
  const int bm = rem / nbn;

  const float* Xblk = X + (size_t)bm * BM * Kstride + sk * Klen;
  const unsigned short* Bblk =
      B + (size_t)bn * BN * Kstride + sk * Klen;

  // A reg-staging geometry: thread -> (row, col-half)
  const int arow = tid >> 1;  // 0..127
  const int ah = tid & 1;     // granules {2ah, 2ah+1}

  auto A_LOAD = [&](float4(&v)[4], int k0) {
    const float* src = Xblk + (size_t)arow * Kstride + k0 + ah * 16;
#pragma unroll
    for (int i = 0; i < 4; ++i)
      v[i] = reinterpret_cast<const float4*>(src)[i];
  };
  auto A_WRITE = [&](int buf, const float4(&v)[4]) {
#pragma unroll
    for (int j = 0; j < 2; ++j) {
      short8 o;
      o[0] = (short)f32_to_bf16(v[2 * j].x);
      o[1] = (short)f32_to_bf16(v[2 * j].y);
      o[2] = (short)f32_to_bf16(v[2 * j].z);
      o[3] = (short)f32_to_bf16(v[2 * j].w);
      o[4] = (short)f32_to_bf16(v[2 * j + 1].x);
      o[5] = (short)f32_to_bf16(v[2 * j + 1].y);
      o[6] = (short)f32_to_bf16(v[2 * j + 1].z);
      o[7] = (short)f32_to_bf16(v[2 * j + 1].w);
      const int g = (2 * ah + j) ^ swz4(arow);
      *reinterpret_cast<short8*>(&As[buf][arow * BK + g * 8]) = o;
    }
  };

  // B staging: 2 gload rounds (64 rows each), inverse-swizzled source
  const int srow = tid >> 2;
  const int sgr = tid & 3;
  auto B_STAGE = [&](int buf, int k0) {
#pragma unroll
    for (int r = 0; r < 2; ++r) {
      const int rr = srow + r * 64;
      const int g = sgr ^ swz4(rr);
      gload_lds16(Bblk + (size_t)rr * Kstride + k0 + g * 8,
                  (void*)&Bs[buf][r * 2048 + tid * 8]);
    }
  };

  const int fr = lane & 15;
  const int hi = lane >> 4;

  f32x4 acc[4][4] = {};

  // prologue
  float4 av[4];
  A_LOAD(av, 0);
  B_STAGE(0, 0);
  A_WRITE(0, av);
  __syncthreads();

#pragma unroll 1
  for (int t = 0; t < ntT; ++t) {
    const int buf = t & 1;
    float4 nv[4];
    if (t + 1 < ntT) {
      A_LOAD(nv, (t + 1) * BK);      // issue early: MFMA covers HBM latency
      B_STAGE(buf ^ 1, (t + 1) * BK);
    }

    short8 af[4], bfr[4];
#pragma unroll
    for (int m = 0; m < 4; ++m) {
      const int row = wrow * 64 + m * 16 + fr;
      const int g = hi ^ swz4(row);
      af[m] = *reinterpret_cast<const short8*>(&As[buf][row * BK + g * 8]);
    }
#pragma unroll
    for (int n = 0; n < 4; ++n) {
      const int row = wcol * 64 + n * 16 + fr;
      const int g = hi ^ swz4(row);
      bfr[n] = *reinterpret_cast<const short8*>(&Bs[buf][row * BK + g * 8]);
    }
#pragma unroll
    for (int m = 0; m < 4; ++m)
#pragma unroll
      for (int n = 0; n < 4; ++n)
        acc[m][n] = __builtin_amdgcn_mfma_f32_16x16x32_bf16(af[m], bfr[n],
                                                            acc[m][n], 0, 0, 0);

    if (t + 1 < ntT) A_WRITE(buf ^ 1, nv);  // write late into the dead buffer
    __syncthreads();
  }

  // epilogue: f32 partial, coalesced
  const int rowbase = bm * BM + wrow * 64 + hi * 4;
  const int colbase = bn * BN + wcol * 64 + fr;
  float* Cblk = Cout + (size_t)sk * BATCH * HID;
#pragma unroll
  for (int n = 0; n < 4; ++n)
#pragma unroll
    for (int m = 0; m < 4; ++m)
#pragma unroll
      for (int r = 0; r < 4; ++r) {
        size_t idx = (size_t)(rowbase + m * 16 + r) * HID + (colbase + n * 16);
        Cblk[idx] = acc[m][n][r];
      }
}

// GEMM2 (round-11 verbatim): m97-style 2-phase, 128x128, BK=32, 4 waves,
// 768 blocks = 3/CU. bias + sigmoid, NT f32 store.
__global__ __launch_bounds__(256) void gemm2s(
    const unsigned short* __restrict__ A, const unsigned short* __restrict__ B,
    const float* __restrict__ bias, float* __restrict__ Cout) {
  constexpr int BM = 128, BN = 128, BK = 32;
  constexpr int Kstride = HID;      // 1024
  constexpr int ntT = Kstride / BK; // 32
  constexpr int nbn = IN_DIM / BN;  // 24
  constexpr int Nout = IN_DIM;

  __shared__ unsigned short As[2][BM * BK];
  __shared__ unsigned short Bs[2][BN * BK];

  const int tid = threadIdx.x;
  const int wave = tid >> 6;
  const int lane = tid & 63;
  const int wrow = wave >> 1, wcol = wave & 1;

  const int nwg = gridDim.x;  // 768
  const int swz = (blockIdx.x & 7) * (nwg >> 3) + (blockIdx.x >> 3);
  const int bn = swz % nbn;
  const int bm = swz / nbn;

  const unsigned short* Ablk = A + (size_t)bm * BM * Kstride;
  const unsigned short* Bblk = B + (size_t)bn * BN * Kstride;

  const int srow = tid >> 2;
  const int sgr = tid & 3;

  auto STAGE = [&](int buf, int k0) {
#pragma unroll
    for (int r = 0; r < 4; ++r) {
      const int rr = srow + (r & 1) * 64;
      const int g = sgr ^ swz4(rr);
      if (r < 2)
        gload_lds16(Ablk + (size_t)rr * Kstride + k0 + g * 8,
                    (void*)&As[buf][(r & 1) * 2048 + tid * 8]);
      else
        gload_lds16(Bblk + (size_t)rr * Kstride + k0 + g * 8,
                    (void*)&Bs[buf][(r & 1) * 2048 + tid * 8]);
    }
  };

  const int fr = lane & 15;
  const int hi = lane >> 4;

  f32x4 acc[4][4] = {};

  STAGE(0, 0);
#pragma unroll 1
  for (int t = 0; t < ntT; ++t) {
    const int buf = t & 1;
    __syncthreads();
    if (t + 1 < ntT) STAGE(buf ^ 1, (t + 1) * BK);

    short8 af[4], bfr[4];
#pragma unroll
    for (int m = 0; m < 4; ++m) {
      const int row = wrow * 64 + m * 16 + fr;
      const int g = hi ^ swz4(row);
      af[m] = *reinterpret_cast<const short8*>(&As[buf][row * BK + g * 8]);
    }
#pragma unroll
    for (int n = 0; n < 4; ++n) {
      const int row = wcol * 64 + n * 16 + fr;
      const int g = hi ^ swz4(row);
      bfr[n] = *reinterpret_cast<const short8*>(&Bs[buf][row * BK + g * 8]);
    }
#pragma unroll
    for (int m = 0; m < 4; ++m)
#pragma unroll
      for (int n = 0; n < 4; ++n)
        acc[m][n] = __builtin_amdgcn_mfma_f32_16x16x32_bf16(af[m], bfr[n],
                                                            acc[m][n], 0, 0, 0);
  }

  const int rowbase = bm * BM + wrow * 64 + hi * 4;
  const int colbase = bn * BN + wcol * 64 + fr;
#pragma unroll
  for (int n = 0; n < 4; ++n) {
    const float bv = bias[colbase + n * 16];
#pragma unroll
    for (int m = 0; m < 4; ++m)
#pragma unroll
      for (int r = 0; r < 4; ++r) {
        float v = acc[m][n][r] + bv;
        v = 1.0f / (1.0f + __expf(-v));
        size_t idx = (size_t)(rowbase + m * 16 + r) * Nout + (colbase + n * 16);
        __builtin_nontemporal_store(v, &Cout[idx]);
      }
  }
}

extern "C" void kernel_launch(void* const* d_in, const int* in_sizes, int n_in,
                              void* d_out, int out_size, void* d_ws,
                              size_t ws_size, hipStream_t stream) {
  const float* x = (const float*)d_in[0];
  const float* We = (const float*)d_in[1];
  const float* be = (const float*)d_in[2];
  const float* Wd = (const float*)d_in[3];
  const float* bd = (const float*)d_in[4];

  float* out = (float*)d_out;                 // [4096,3072]
  float* hid = out + (size_t)BATCH * IN_DIM;  // [4096,1024]
  // split-K=2 f32 partials (33.6MB) in the out region (50MB); GEMM2 last.
  float* part = out;

  unsigned short* Web = (unsigned short*)d_ws;         // bf16 We  [1024,3072]
  unsigned short* Wdb = Web + (size_t)HID * IN_DIM;    // bf16 Wd  [3072,1024]
  unsigned short* hb = Wdb + (size_t)IN_DIM * HID;     // bf16 hid [4096,1024]

  cvt2_kernel<<<1024, 256, 0, stream>>>(We, Wd, Web, Wdb, HID * IN_DIM / 4,
                                        IN_DIM * HID / 4);

  // GEMM1: f32-A reg-staged partials of x @ We^T. split-K=2 -> 512 blocks
  gemm1r<<<512, 256, 0, stream>>>(x, Web, part);

  // ODE: gamma = p0+p1+be, RK4 -> hid f32 (NT) + hb bf16
  ode_kernel<<<2048, 256, 0, stream>>>(part, part + (size_t)BATCH * HID, be,
                                       hid, hb, BATCH * HID / 4);

  // GEMM2: out = sigmoid(y @ Wd^T + bd). 768 blocks = 3/CU
  gemm2s<<<768, 256, 0, stream>>>(hb, Wdb, bd, out);
}

// Round 13
// 118.284 us; speedup vs baseline: 1.0224x; 1.0224x over previous
//
#include <hip/hip_runtime.h>
#include <hip/hip_bf16.h>

#define BATCH 4096
#define IN_DIM 3072
#define HID 1024
#define NSTEP 6

typedef __attribute__((ext_vector_type(8))) short short8;
typedef __attribute__((ext_vector_type(4))) float f32x4;
typedef __attribute__((ext_vector_type(4))) unsigned short ushort4v;

__device__ __forceinline__ void gload_lds16(const void* g, void* lds) {
  __builtin_amdgcn_global_load_lds(
      (const __attribute__((address_space(1))) void*)g,
      (__attribute__((address_space(3))) void*)lds, 16, 0, 0);
}

__device__ __forceinline__ unsigned short f32_to_bf16(float f) {
  unsigned int u = __builtin_bit_cast(unsigned int, f);
  unsigned int r = u + 0x7fffu + ((u >> 16) & 1u);
  return (unsigned short)(r >> 16);
}

// compiler-motion fence + HW barrier + scheduler pin
#define BARX()                          \
  do {                                  \
    asm volatile("" ::: "memory");      \
    __builtin_amdgcn_s_barrier();       \
    __builtin_amdgcn_sched_barrier(0);  \
  } while (0)

#define LGKM0()                                        \
  do {                                                 \
    asm volatile("s_waitcnt lgkmcnt(0)" ::: "memory"); \
    __builtin_amdgcn_sched_barrier(0);                 \
  } while (0)

#define VMCNT(N)                                            \
  do {                                                      \
    asm volatile("s_waitcnt vmcnt(" #N ")" ::: "memory");   \
    __builtin_amdgcn_sched_barrier(0);                      \
  } while (0)

// BK=64 swizzle (row&7, proven 0-conflict) / BK=32 swizzle (2-way, free)
__device__ __forceinline__ int swz4(int r) { return (r & 3) ^ ((r >> 2) & 3); }

// fused f32 -> bf16 conversion of x, We, Wd (one launch)
__global__ void cvt3_kernel(const float* __restrict__ a,
                            const float* __restrict__ b,
                            const float* __restrict__ c,
                            unsigned short* __restrict__ da,
                            unsigned short* __restrict__ db,
                            unsigned short* __restrict__ dc, int na, int nb,
                            int nc) {
  const int total = na + nb + nc;
  const int stride = gridDim.x * blockDim.x;
  for (int i = blockIdx.x * blockDim.x + threadIdx.x; i < total; i += stride) {
    const float* s;
    unsigned short* d;
    int j = i;
    if (j < na) {
      s = a; d = da;
    } else if (j < na + nb) {
      s = b; d = db; j -= na;
    } else {
      s = c; d = dc; j -= na + nb;
    }
    const float4 v = reinterpret_cast<const float4*>(s)[j];
    ushort4v o;
    o.x = f32_to_bf16(v.x);
    o.y = f32_to_bf16(v.y);
    o.z = f32_to_bf16(v.z);
    o.w = f32_to_bf16(v.w);
    reinterpret_cast<ushort4v*>(d)[j] = o;
  }
}

// Split-K2 reduce (p0+p1+bias) + RK4 nmODE. Writes y f32 (NT) + bf16.
__global__ __launch_bounds__(256) void ode_kernel(
    const float* __restrict__ p0, const float* __restrict__ p1,
    const float* __restrict__ be, float* __restrict__ hid,
    unsigned short* __restrict__ hb, int n4) {
  const float dt = 1.0f / (float)NSTEP;
  const float h2 = 0.5f * dt, hd = dt, h6 = dt / 6.0f;
  int stride = gridDim.x * blockDim.x;
  for (int i = blockIdx.x * blockDim.x + threadIdx.x; i < n4; i += stride) {
    const float4 a4 = reinterpret_cast<const float4*>(p0)[i];
    const float4 b4 = reinterpret_cast<const float4*>(p1)[i];
    const float4 e4 = reinterpret_cast<const float4*>(be)[i & (HID / 4 - 1)];
    float g[4] = {a4.x + b4.x + e4.x, a4.y + b4.y + e4.y,
                  a4.z + b4.z + e4.z, a4.w + b4.w + e4.w};
    float y[4] = {0.0f, 0.0f, 0.0f, 0.0f};
#pragma unroll 1
    for (int s = 0; s < NSTEP; ++s) {
      float k1[4], k2[4], k3[4], k4[4];
#pragma unroll
      for (int e = 0; e < 4; ++e) {
        float t = __sinf(y[e] + g[e]);
        k1[e] = t * t - y[e];
      }
#pragma unroll
      for (int e = 0; e < 4; ++e) {
        float yy = fmaf(h2, k1[e], y[e]);
        float t = __sinf(yy + g[e]);
        k2[e] = t * t - yy;
      }
#pragma unroll
      for (int e = 0; e < 4; ++e) {
        float yy = fmaf(h2, k2[e], y[e]);
        float t = __sinf(yy + g[e]);
        k3[e] = t * t - yy;
      }
#pragma unroll
      for (int e = 0; e < 4; ++e) {
        float yy = fmaf(hd, k3[e], y[e]);
        float t = __sinf(yy + g[e]);
        k4[e] = t * t - yy;
      }
#pragma unroll
      for (int e = 0; e < 4; ++e) {
        float ks = k1[e] + 2.0f * (k2[e] + k3[e]) + k4[e];
        y[e] = fmaf(h6, ks, y[e]);
      }
    }
    f32x4 o4;
    o4[0] = y[0]; o4[1] = y[1]; o4[2] = y[2]; o4[3] = y[3];
    __builtin_nontemporal_store(o4, &reinterpret_cast<f32x4*>(hid)[i]);
    ushort4v ob;
    ob.x = f32_to_bf16(y[0]);
    ob.y = f32_to_bf16(y[1]);
    ob.z = f32_to_bf16(y[2]);
    ob.w = f32_to_bf16(y[3]);
    reinterpret_cast<ushort4v*>(hb)[i] = ob;
  }
}

// GEMM1 (round-10 verbatim, measured ~42us): partials of x @ We^T.
// BM=256, BN=128, BK=64, split-K=2, 8 waves (2x4), per-wave 128x32.
// Two double-barrier phases per K-tile, counted vmcnt (never 0 in loop),
// row&7 granule XOR swizzle. f32 partial at Cout + sk*BATCH*HID.
__global__ __launch_bounds__(512, 2) void gemm1k(
    const unsigned short* __restrict__ A, const unsigned short* __restrict__ B,
    float* __restrict__ Cout) {
  constexpr int BM = 256, BN = 128, BK = 64;
  constexpr int Kstride = IN_DIM;       // 3072
  constexpr int Klen = Kstride / 2;     // 1536
  constexpr int ntT = Klen / BK;        // 24
  constexpr int nbm = BATCH / BM;       // 16
  constexpr int nbn = HID / BN;         // 8

  __shared__ unsigned short As[2][BM * BK];
  __shared__ unsigned short Bs[2][BN * BK];

  const int tid = threadIdx.x;
  const int wave = tid >> 6;
  const int lane = tid & 63;
  const int wrow = wave >> 2;
  const int wcol = wave & 3;

  const int nwg = gridDim.x;  // 256
  const int swz = (blockIdx.x & 7) * (nwg >> 3) + (blockIdx.x >> 3);
  const int tiles = nbm * nbn;  // 128
  const int sk = swz / tiles;
  const int rem = swz % tiles;
  const int bn = rem % nbn;
  const int bm = rem / nbn;

  const unsigned short* Ablk = A + (size_t)bm * BM * Kstride + sk * Klen;
  const unsigned short* Bblk = B + (size_t)bn * BN * Kstride + sk * Klen;

  const int srr = tid >> 3;
  const int sgl = tid & 7;

  auto STAGE = [&](int buf, int k0, int r) {
    if (r < 4) {
      const int row = r * 64 + srr;
      const int g = sgl ^ (row & 7);
      gload_lds16(Ablk + (size_t)row * Kstride + k0 + g * 8,
                  (void*)&As[buf][r * 4096 + wave * 512]);
    } else {
      const int row = (r - 4) * 64 + srr;
      const int g = sgl ^ (row & 7);
      gload_lds16(Bblk + (size_t)row * Kstride + k0 + g * 8,
                  (void*)&Bs[buf][(r - 4) * 4096 + wave * 512]);
    }
  };

  const int fr = lane & 15;
  const int hi = lane >> 4;

  short8 a[4][2], b1[2][2];
  f32x4 acc[8][2] = {};

  auto READ_A = [&](int buf, int mh) {
#pragma unroll
    for (int m = 0; m < 4; ++m) {
      const int row = wrow * 128 + (mh * 4 + m) * 16 + fr;
#pragma unroll
      for (int kk = 0; kk < 2; ++kk) {
        const int g = (kk * 4 + hi) ^ (row & 7);
        a[m][kk] =
            *reinterpret_cast<const short8*>(&As[buf][row * BK + g * 8]);
      }
    }
  };
  auto READ_B = [&](int buf) {
#pragma unroll
    for (int n = 0; n < 2; ++n) {
      const int row = wcol * 32 + n * 16 + fr;
#pragma unroll
      for (int kk = 0; kk < 2; ++kk) {
        const int g = (kk * 4 + hi) ^ (row & 7);
        b1[n][kk] =
            *reinterpret_cast<const short8*>(&Bs[buf][row * BK + g * 8]);
      }
    }
  };
  auto MM = [&](int mh) {
#pragma unroll
    for (int kk = 0; kk < 2; ++kk)
#pragma unroll
      for (int m = 0; m < 4; ++m)
#pragma unroll
        for (int n = 0; n < 2; ++n)
          acc[mh * 4 + m][n] = __builtin_amdgcn_mfma_f32_16x16x32_bf16(
              a[m][kk], b1[n][kk], acc[mh * 4 + m][n], 0, 0, 0);
  };

  STAGE(0, 0, 0); STAGE(0, 0, 2); STAGE(0, 0, 4); STAGE(0, 0, 5);
  STAGE(0, 0, 1); STAGE(0, 0, 3);
  VMCNT(2);
  BARX();

#pragma unroll 1
  for (int t = 0; t < ntT; ++t) {
    const int b = t & 1;
    const int kn = ((t + 1 == ntT) ? 0 : t + 1) * BK;
    // ph1
    READ_A(b, 0);
    READ_B(b);
    STAGE(b ^ 1, kn, 0); STAGE(b ^ 1, kn, 2);
    STAGE(b ^ 1, kn, 4); STAGE(b ^ 1, kn, 5);
    VMCNT(4);
    BARX(); LGKM0();
    __builtin_amdgcn_s_setprio(1); MM(0);
    __builtin_amdgcn_s_setprio(0); BARX();
    // ph2
    READ_A(b, 1);
    STAGE(b ^ 1, kn, 1); STAGE(b ^ 1, kn, 3);
    VMCNT(2);
    BARX(); LGKM0();
    __builtin_amdgcn_s_setprio(1); MM(1);
    __builtin_amdgcn_s_setprio(0); BARX();
  }

  const int rowbase = bm * BM + wrow * 128 + hi * 4;
  const int colbase = bn * BN + wcol * 32 + fr;
  float* Cblk = Cout + (size_t)sk * BATCH * HID;
#pragma unroll
  for (int m = 0; m < 8; ++m)
#pragma unroll
    for (int n = 0; n < 2; ++n)
#pragma unroll
      for (int r = 0; r < 4; ++r) {
        size_t idx =
            (size_t)(rowbase + m * 16 + r) * HID + (colbase + n * 16);
        Cblk[idx] = acc[m][n][r];
      }
}

// GEMM2: m97 2-phase at 4 blocks/CU. 128x96 tile, BK=32, 4 waves (2x2,
// per-wave 64x48, acc 4x3), grid 32x32=1024 = exactly 4/CU, LDS 28 KB.
// Staging: 896 16B-units in 3.5 wave-complete rounds (A units 0..511,
// B units 512..895; every 64-unit wave chunk lies in one region, so the
// gload_lds wave-uniform-dest contract holds). Swizzle rule #21.
__global__ __launch_bounds__(256) void gemm2s(
    const unsigned short* __restrict__ A, const unsigned short* __restrict__ B,
    const float* __restrict__ bias, float* __restrict__ Cout) {
  constexpr int BM = 128, BN = 96, BK = 32;
  constexpr int Kstride = HID;       // 1024
  constexpr int ntT = Kstride / BK;  // 32
  constexpr int nbn = IN_DIM / BN;   // 32
  constexpr int Nout = IN_DIM;
  constexpr int UA = BM * 4;         // 512 16B-units in A tile
  constexpr int UT = UA + BN * 4;    // 896 total

  __shared__ unsigned short As[2][BM * BK];
  __shared__ unsigned short Bs[2][BN * BK];

  const int tid = threadIdx.x;
  const int wave = tid >> 6;
  const int lane = tid & 63;
  const int wrow = wave >> 1, wcol = wave & 1;

  const int nwg = gridDim.x;  // 1024
  const int swz = (blockIdx.x & 7) * (nwg >> 3) + (blockIdx.x >> 3);
  const int bn = swz % nbn;
  const int bm = swz / nbn;

  const unsigned short* Ablk = A + (size_t)bm * BM * Kstride;
  const unsigned short* Bblk = B + (size_t)bn * BN * Kstride;

  auto STAGE = [&](int buf, int k0) {
#pragma unroll
    for (int i = 0; i < 4; ++i) {
      const int u = i * 256 + tid;
      if (i < 3 || u < UT) {  // wave-uniform predicate (64-unit granularity)
        if (u < UA) {
          const int row = u >> 2;
          const int g = (u & 3) ^ swz4(row);
          gload_lds16(Ablk + (size_t)row * Kstride + k0 + g * 8,
                      (void*)&As[buf][u * 8]);
        } else {
          const int ub = u - UA;
          const int row = ub >> 2;
          const int g = (ub & 3) ^ swz4(row);
          gload_lds16(Bblk + (size_t)row * Kstride + k0 + g * 8,
                      (void*)&Bs[buf][ub * 8]);
        }
      }
    }
  };

  const int fr = lane & 15;
  const int hi = lane >> 4;

  f32x4 acc[4][3] = {};

  STAGE(0, 0);
#pragma unroll 1
  for (int t = 0; t < ntT; ++t) {
    const int buf = t & 1;
    __syncthreads();  // compiler drains vmcnt/lgkm: tile t resident
    if (t + 1 < ntT) STAGE(buf ^ 1, (t + 1) * BK);

    short8 af[4], bfr[3];
#pragma unroll
    for (int m = 0; m < 4; ++m) {
      const int row = wrow * 64 + m * 16 + fr;
      const int g = hi ^ swz4(row);
      af[m] = *reinterpret_cast<const short8*>(&As[buf][row * BK + g * 8]);
    }
#pragma unroll
    for (int n = 0; n < 3; ++n) {
      const int row = wcol * 48 + n * 16 + fr;
      const int g = hi ^ swz4(row);
      bfr[n] = *reinterpret_cast<const short8*>(&Bs[buf][row * BK + g * 8]);
    }
#pragma unroll
    for (int m = 0; m < 4; ++m)
#pragma unroll
      for (int n = 0; n < 3; ++n)
        acc[m][n] = __builtin_amdgcn_mfma_f32_16x16x32_bf16(af[m], bfr[n],
                                                            acc[m][n], 0, 0, 0);
  }

  const int rowbase = bm * BM + wrow * 64 + hi * 4;
  const int colbase = bn * BN + wcol * 48 + fr;
#pragma unroll
  for (int n = 0; n < 3; ++n) {
    const float bv = bias[colbase + n * 16];
#pragma unroll
    for (int m = 0; m < 4; ++m)
#pragma unroll
      for (int r = 0; r < 4; ++r) {
        float v = acc[m][n][r] + bv;
        v = 1.0f / (1.0f + __expf(-v));
        size_t idx = (size_t)(rowbase + m * 16 + r) * Nout + (colbase + n * 16);
        __builtin_nontemporal_store(v, &Cout[idx]);
      }
  }
}

extern "C" void kernel_launch(void* const* d_in, const int* in_sizes, int n_in,
                              void* d_out, int out_size, void* d_ws,
                              size_t ws_size, hipStream_t stream) {
  const float* x = (const float*)d_in[0];
  const float* We = (const float*)d_in[1];
  const float* be = (const float*)d_in[2];
  const float* Wd = (const float*)d_in[3];
  const float* bd = (const float*)d_in[4];

  float* out = (float*)d_out;                 // [4096,3072]
  float* hid = out + (size_t)BATCH * IN_DIM;  // [4096,1024]
  // split-K=2 f32 partials (33.6MB) in the out region (50MB); GEMM2 last.
  float* part = out;

  unsigned short* xb = (unsigned short*)d_ws;          // bf16 x   [4096,3072]
  unsigned short* Web = xb + (size_t)BATCH * IN_DIM;   // bf16 We  [1024,3072]
  unsigned short* Wdb = Web + (size_t)HID * IN_DIM;    // bf16 Wd  [3072,1024]
  unsigned short* hb = Wdb + (size_t)IN_DIM * HID;     // bf16 hid [4096,1024]

  cvt3_kernel<<<2048, 256, 0, stream>>>(
      x, We, Wd, xb, Web, Wdb, BATCH * IN_DIM / 4, HID * IN_DIM / 4,
      IN_DIM * HID / 4);

  // GEMM1: f32 partials of x @ We^T. 256x128, BK=64, split-K=2 -> 256 blocks
  gemm1k<<<256, 512, 0, stream>>>(xb, Web, part);

  // ODE: gamma = p0+p1+be, RK4 -> hid f32 (NT) + hb bf16
  ode_kernel<<<2048, 256, 0, stream>>>(part, part + (size_t)BATCH * HID, be,
                                       hid, hb, BATCH * HID / 4);

  // GEMM2: out = sigmoid(y @ Wd^T + bd). 128x96 -> 1024 blocks = 4/CU
  gemm2s<<<1024, 256, 0, stream>>>(hb, Wdb, bd, out);
}

// Round 14
// 115.774 us; speedup vs baseline: 1.0446x; 1.0217x over previous
//
#include <hip/hip_runtime.h>
#include <hip/hip_bf16.h>

#define BATCH 4096
#define IN_DIM 3072
#define HID 1024
#define NSTEP 6

typedef __attribute__((ext_vector_type(8))) short short8;
typedef __attribute__((ext_vector_type(4))) float f32x4;
typedef __attribute__((ext_vector_type(4))) unsigned short ushort4v;

__device__ __forceinline__ void gload_lds16(const void* g, void* lds) {
  __builtin_amdgcn_global_load_lds(
      (const __attribute__((address_space(1))) void*)g,
      (__attribute__((address_space(3))) void*)lds, 16, 0, 0);
}

__device__ __forceinline__ unsigned short f32_to_bf16(float f) {
  unsigned int u = __builtin_bit_cast(unsigned int, f);
  unsigned int r = u + 0x7fffu + ((u >> 16) & 1u);
  return (unsigned short)(r >> 16);
}

// BK=32 granule swizzle (residual 2-way aliasing only — free, m136)
__device__ __forceinline__ int swz4(int r) { return (r & 3) ^ ((r >> 2) & 3); }

// fused f32 -> bf16 conversion of x, We, Wd (one launch)
__global__ void cvt3_kernel(const float* __restrict__ a,
                            const float* __restrict__ b,
                            const float* __restrict__ c,
                            unsigned short* __restrict__ da,
                            unsigned short* __restrict__ db,
                            unsigned short* __restrict__ dc, int na, int nb,
                            int nc) {
  const int total = na + nb + nc;
  const int stride = gridDim.x * blockDim.x;
  for (int i = blockIdx.x * blockDim.x + threadIdx.x; i < total; i += stride) {
    const float* s;
    unsigned short* d;
    int j = i;
    if (j < na) {
      s = a; d = da;
    } else if (j < na + nb) {
      s = b; d = db; j -= na;
    } else {
      s = c; d = dc; j -= na + nb;
    }
    const float4 v = reinterpret_cast<const float4*>(s)[j];
    ushort4v o;
    o.x = f32_to_bf16(v.x);
    o.y = f32_to_bf16(v.y);
    o.z = f32_to_bf16(v.z);
    o.w = f32_to_bf16(v.w);
    reinterpret_cast<ushort4v*>(d)[j] = o;
  }
}

// Split-K2 reduce (p0+p1+bias) + RK4 nmODE. Writes y f32 (NT) + bf16.
__global__ __launch_bounds__(256) void ode_kernel(
    const float* __restrict__ p0, const float* __restrict__ p1,
    const float* __restrict__ be, float* __restrict__ hid,
    unsigned short* __restrict__ hb, int n4) {
  const float dt = 1.0f / (float)NSTEP;
  const float h2 = 0.5f * dt, hd = dt, h6 = dt / 6.0f;
  int stride = gridDim.x * blockDim.x;
  for (int i = blockIdx.x * blockDim.x + threadIdx.x; i < n4; i += stride) {
    const float4 a4 = reinterpret_cast<const float4*>(p0)[i];
    const float4 b4 = reinterpret_cast<const float4*>(p1)[i];
    const float4 e4 = reinterpret_cast<const float4*>(be)[i & (HID / 4 - 1)];
    float g[4] = {a4.x + b4.x + e4.x, a4.y + b4.y + e4.y,
                  a4.z + b4.z + e4.z, a4.w + b4.w + e4.w};
    float y[4] = {0.0f, 0.0f, 0.0f, 0.0f};
#pragma unroll 1
    for (int s = 0; s < NSTEP; ++s) {
      float k1[4], k2[4], k3[4], k4[4];
#pragma unroll
      for (int e = 0; e < 4; ++e) {
        float t = __sinf(y[e] + g[e]);
        k1[e] = t * t - y[e];
      }
#pragma unroll
      for (int e = 0; e < 4; ++e) {
        float yy = fmaf(h2, k1[e], y[e]);
        float t = __sinf(yy + g[e]);
        k2[e] = t * t - yy;
      }
#pragma unroll
      for (int e = 0; e < 4; ++e) {
        float yy = fmaf(h2, k2[e], y[e]);
        float t = __sinf(yy + g[e]);
        k3[e] = t * t - yy;
      }
#pragma unroll
      for (int e = 0; e < 4; ++e) {
        float yy = fmaf(hd, k3[e], y[e]);
        float t = __sinf(yy + g[e]);
        k4[e] = t * t - yy;
      }
#pragma unroll
      for (int e = 0; e < 4; ++e) {
        float ks = k1[e] + 2.0f * (k2[e] + k3[e]) + k4[e];
        y[e] = fmaf(h6, ks, y[e]);
      }
    }
    f32x4 o4;
    o4[0] = y[0]; o4[1] = y[1]; o4[2] = y[2]; o4[3] = y[3];
    __builtin_nontemporal_store(o4, &reinterpret_cast<f32x4*>(hid)[i]);
    ushort4v ob;
    ob.x = f32_to_bf16(y[0]);
    ob.y = f32_to_bf16(y[1]);
    ob.z = f32_to_bf16(y[2]);
    ob.w = f32_to_bf16(y[3]);
    reinterpret_cast<ushort4v*>(hb)[i] = ob;
  }
}

// GEMM1: fully-specialized 2-phase (R12-gemm2s structure). Partials of
// x @ We^T. 128x128, BK=32, 4 waves (2x2), split-K=2 -> 512 blocks (2/CU,
// 32 KB LDS). All strides constexpr (the R12 finding: runtime-stride
// addressing in STAGE/read paths cost ~25%). Swizzle rule #21.
// f32 partial at Cout + sk*BATCH*HID, coalesced cached store.
__global__ __launch_bounds__(256) void gemm1s(
    const unsigned short* __restrict__ A, const unsigned short* __restrict__ B,
    float* __restrict__ Cout) {
  constexpr int BM = 128, BN = 128, BK = 32;
  constexpr int Kstride = IN_DIM;    // 3072
  constexpr int Klen = Kstride / 2;  // 1536
  constexpr int ntT = Klen / BK;     // 48
  constexpr int nbn = HID / BN;      // 8
  constexpr int nbm = BATCH / BM;    // 32
  constexpr int tiles = nbm * nbn;   // 256

  __shared__ unsigned short As[2][BM * BK];
  __shared__ unsigned short Bs[2][BN * BK];

  const int tid = threadIdx.x;
  const int wave = tid >> 6;
  const int lane = tid & 63;
  const int wrow = wave >> 1, wcol = wave & 1;

  const int nwg = gridDim.x;  // 512
  const int swz = (blockIdx.x & 7) * (nwg >> 3) + (blockIdx.x >> 3);
  const int sk = swz / tiles;
  const int rem = swz % tiles;
  const int bn = rem % nbn;
  const int bm = rem / nbn;

  const unsigned short* Ablk = A + (size_t)bm * BM * Kstride + sk * Klen;
  const unsigned short* Bblk = B + (size_t)bn * BN * Kstride + sk * Klen;

  const int srow = tid >> 2;
  const int sgr = tid & 3;

  auto STAGE = [&](int buf, int k0) {
#pragma unroll
    for (int r = 0; r < 4; ++r) {
      const int rr = srow + (r & 1) * 64;
      const int g = sgr ^ swz4(rr);  // inverse-swizzled global source
      if (r < 2)
        gload_lds16(Ablk + (size_t)rr * Kstride + k0 + g * 8,
                    (void*)&As[buf][(r & 1) * 2048 + tid * 8]);
      else
        gload_lds16(Bblk + (size_t)rr * Kstride + k0 + g * 8,
                    (void*)&Bs[buf][(r & 1) * 2048 + tid * 8]);
    }
  };

  const int fr = lane & 15;
  const int hi = lane >> 4;

  f32x4 acc[4][4] = {};

  STAGE(0, 0);
#pragma unroll 1
  for (int t = 0; t < ntT; ++t) {
    const int buf = t & 1;
    __syncthreads();  // compiler drains vmcnt/lgkm: tile t resident
    if (t + 1 < ntT) STAGE(buf ^ 1, (t + 1) * BK);

    short8 af[4], bfr[4];
#pragma unroll
    for (int m = 0; m < 4; ++m) {
      const int row = wrow * 64 + m * 16 + fr;
      const int g = hi ^ swz4(row);  // swizzled read granule
      af[m] = *reinterpret_cast<const short8*>(&As[buf][row * BK + g * 8]);
    }
#pragma unroll
    for (int n = 0; n < 4; ++n) {
      const int row = wcol * 64 + n * 16 + fr;
      const int g = hi ^ swz4(row);
      bfr[n] = *reinterpret_cast<const short8*>(&Bs[buf][row * BK + g * 8]);
    }
#pragma unroll
    for (int m = 0; m < 4; ++m)
#pragma unroll
      for (int n = 0; n < 4; ++n)
        acc[m][n] = __builtin_amdgcn_mfma_f32_16x16x32_bf16(af[m], bfr[n],
                                                            acc[m][n], 0, 0, 0);
  }

  // epilogue: C/D layout col=lane&15, row=(lane>>4)*4+reg (m89-verified)
  const int rowbase = bm * BM + wrow * 64 + hi * 4;
  const int colbase = bn * BN + wcol * 64 + fr;
  float* Cblk = Cout + (size_t)sk * BATCH * HID;
#pragma unroll
  for (int n = 0; n < 4; ++n)
#pragma unroll
    for (int m = 0; m < 4; ++m)
#pragma unroll
      for (int r = 0; r < 4; ++r) {
        size_t idx = (size_t)(rowbase + m * 16 + r) * HID + (colbase + n * 16);
        Cblk[idx] = acc[m][n][r];
      }
}

// GEMM2 (R12 verbatim, inferred ~33us): specialized m97 2-phase, 128x128,
// BK=32, 4 waves, 768 blocks = 3/CU. bias + sigmoid, NT f32 store.
__global__ __launch_bounds__(256) void gemm2s(
    const unsigned short* __restrict__ A, const unsigned short* __restrict__ B,
    const float* __restrict__ bias, float* __restrict__ Cout) {
  constexpr int BM = 128, BN = 128, BK = 32;
  constexpr int Kstride = HID;      // 1024
  constexpr int ntT = Kstride / BK; // 32
  constexpr int nbn = IN_DIM / BN;  // 24
  constexpr int Nout = IN_DIM;

  __shared__ unsigned short As[2][BM * BK];
  __shared__ unsigned short Bs[2][BN * BK];

  const int tid = threadIdx.x;
  const int wave = tid >> 6;
  const int lane = tid & 63;
  const int wrow = wave >> 1, wcol = wave & 1;

  const int nwg = gridDim.x;  // 768
  const int swz = (blockIdx.x & 7) * (nwg >> 3) + (blockIdx.x >> 3);
  const int bn = swz % nbn;
  const int bm = swz / nbn;

  const unsigned short* Ablk = A + (size_t)bm * BM * Kstride;
  const unsigned short* Bblk = B + (size_t)bn * BN * Kstride;

  const int srow = tid >> 2;
  const int sgr = tid & 3;

  auto STAGE = [&](int buf, int k0) {
#pragma unroll
    for (int r = 0; r < 4; ++r) {
      const int rr = srow + (r & 1) * 64;
      const int g = sgr ^ swz4(rr);
      if (r < 2)
        gload_lds16(Ablk + (size_t)rr * Kstride + k0 + g * 8,
                    (void*)&As[buf][(r & 1) * 2048 + tid * 8]);
      else
        gload_lds16(Bblk + (size_t)rr * Kstride + k0 + g * 8,
                    (void*)&Bs[buf][(r & 1) * 2048 + tid * 8]);
    }
  };

  const int fr = lane & 15;
  const int hi = lane >> 4;

  f32x4 acc[4][4] = {};

  STAGE(0, 0);
#pragma unroll 1
  for (int t = 0; t < ntT; ++t) {
    const int buf = t & 1;
    __syncthreads();
    if (t + 1 < ntT) STAGE(buf ^ 1, (t + 1) * BK);

    short8 af[4], bfr[4];
#pragma unroll
    for (int m = 0; m < 4; ++m) {
      const int row = wrow * 64 + m * 16 + fr;
      const int g = hi ^ swz4(row);
      af[m] = *reinterpret_cast<const short8*>(&As[buf][row * BK + g * 8]);
    }
#pragma unroll
    for (int n = 0; n < 4; ++n) {
      const int row = wcol * 64 + n * 16 + fr;
      const int g = hi ^ swz4(row);
      bfr[n] = *reinterpret_cast<const short8*>(&Bs[buf][row * BK + g * 8]);
    }
#pragma unroll
    for (int m = 0; m < 4; ++m)
#pragma unroll
      for (int n = 0; n < 4; ++n)
        acc[m][n] = __builtin_amdgcn_mfma_f32_16x16x32_bf16(af[m], bfr[n],
                                                            acc[m][n], 0, 0, 0);
  }

  const int rowbase = bm * BM + wrow * 64 + hi * 4;
  const int colbase = bn * BN + wcol * 64 + fr;
#pragma unroll
  for (int n = 0; n < 4; ++n) {
    const float bv = bias[colbase + n * 16];
#pragma unroll
    for (int m = 0; m < 4; ++m)
#pragma unroll
      for (int r = 0; r < 4; ++r) {
        float v = acc[m][n][r] + bv;
        v = 1.0f / (1.0f + __expf(-v));
        size_t idx = (size_t)(rowbase + m * 16 + r) * Nout + (colbase + n * 16);
        __builtin_nontemporal_store(v, &Cout[idx]);
      }
  }
}

extern "C" void kernel_launch(void* const* d_in, const int* in_sizes, int n_in,
                              void* d_out, int out_size, void* d_ws,
                              size_t ws_size, hipStream_t stream) {
  const float* x = (const float*)d_in[0];
  const float* We = (const float*)d_in[1];
  const float* be = (const float*)d_in[2];
  const float* Wd = (const float*)d_in[3];
  const float* bd = (const float*)d_in[4];

  float* out = (float*)d_out;                 // [4096,3072]
  float* hid = out + (size_t)BATCH * IN_DIM;  // [4096,1024]
  // split-K=2 f32 partials (33.6MB) in the out region (50MB); GEMM2 last.
  float* part = out;

  unsigned short* xb = (unsigned short*)d_ws;          // bf16 x   [4096,3072]
  unsigned short* Web = xb + (size_t)BATCH * IN_DIM;   // bf16 We  [1024,3072]
  unsigned short* Wdb = Web + (size_t)HID * IN_DIM;    // bf16 Wd  [3072,1024]
  unsigned short* hb = Wdb + (size_t)IN_DIM * HID;     // bf16 hid [4096,1024]

  cvt3_kernel<<<2048, 256, 0, stream>>>(
      x, We, Wd, xb, Web, Wdb, BATCH * IN_DIM / 4, HID * IN_DIM / 4,
      IN_DIM * HID / 4);

  // GEMM1: specialized 2-phase, f32 partials of x @ We^T. split-K=2,
  // 512 blocks = 2/CU fully resident.
  gemm1s<<<512, 256, 0, stream>>>(xb, Web, part);

  // ODE: gamma = p0+p1+be, RK4 -> hid f32 (NT) + hb bf16
  ode_kernel<<<2048, 256, 0, stream>>>(part, part + (size_t)BATCH * HID, be,
                                       hid, hb, BATCH * HID / 4);

  // GEMM2: out = sigmoid(y @ Wd^T + bd). 768 blocks = 3/CU
  gemm2s<<<768, 256, 0, stream>>>(hb, Wdb, bd, out);
}

// Round 15
// 109.910 us; speedup vs baseline: 1.1003x; 1.0533x over previous
//
#include <hip/hip_runtime.h>
#include <hip/hip_bf16.h>

#define BATCH 4096
#define IN_DIM 3072
#define HID 1024
#define NSTEP 6

typedef __attribute__((ext_vector_type(8))) short short8;
typedef __attribute__((ext_vector_type(4))) float f32x4;
typedef __attribute__((ext_vector_type(4))) unsigned short ushort4v;

__device__ __forceinline__ void gload_lds16(const void* g, void* lds) {
  __builtin_amdgcn_global_load_lds(
      (const __attribute__((address_space(1))) void*)g,
      (__attribute__((address_space(3))) void*)lds, 16, 0, 0);
}

__device__ __forceinline__ unsigned short f32_to_bf16(float f) {
  unsigned int u = __builtin_bit_cast(unsigned int, f);
  unsigned int r = u + 0x7fffu + ((u >> 16) & 1u);
  return (unsigned short)(r >> 16);
}

// BK=32 granule swizzle (residual 2-way aliasing only — free, m136)
__device__ __forceinline__ int swz4(int r) { return (r & 3) ^ ((r >> 2) & 3); }

// fused f32 -> bf16 conversion of x, We, Wd (one launch)
__global__ void cvt3_kernel(const float* __restrict__ a,
                            const float* __restrict__ b,
                            const float* __restrict__ c,
                            unsigned short* __restrict__ da,
                            unsigned short* __restrict__ db,
                            unsigned short* __restrict__ dc, int na, int nb,
                            int nc) {
  const int total = na + nb + nc;
  const int stride = gridDim.x * blockDim.x;
  for (int i = blockIdx.x * blockDim.x + threadIdx.x; i < total; i += stride) {
    const float* s;
    unsigned short* d;
    int j = i;
    if (j < na) {
      s = a; d = da;
    } else if (j < na + nb) {
      s = b; d = db; j -= na;
    } else {
      s = c; d = dc; j -= na + nb;
    }
    const float4 v = reinterpret_cast<const float4*>(s)[j];
    ushort4v o;
    o.x = f32_to_bf16(v.x);
    o.y = f32_to_bf16(v.y);
    o.z = f32_to_bf16(v.z);
    o.w = f32_to_bf16(v.w);
    reinterpret_cast<ushort4v*>(d)[j] = o;
  }
}

// Split-K2 reduce (p0+p1+bias) + RK4 nmODE. Writes y f32 (NT) + bf16.
__global__ __launch_bounds__(256) void ode_kernel(
    const float* __restrict__ p0, const float* __restrict__ p1,
    const float* __restrict__ be, float* __restrict__ hid,
    unsigned short* __restrict__ hb, int n4) {
  const float dt = 1.0f / (float)NSTEP;
  const float h2 = 0.5f * dt, hd = dt, h6 = dt / 6.0f;
  int stride = gridDim.x * blockDim.x;
  for (int i = blockIdx.x * blockDim.x + threadIdx.x; i < n4; i += stride) {
    const float4 a4 = reinterpret_cast<const float4*>(p0)[i];
    const float4 b4 = reinterpret_cast<const float4*>(p1)[i];
    const float4 e4 = reinterpret_cast<const float4*>(be)[i & (HID / 4 - 1)];
    float g[4] = {a4.x + b4.x + e4.x, a4.y + b4.y + e4.y,
                  a4.z + b4.z + e4.z, a4.w + b4.w + e4.w};
    float y[4] = {0.0f, 0.0f, 0.0f, 0.0f};
#pragma unroll 1
    for (int s = 0; s < NSTEP; ++s) {
      float k1[4], k2[4], k3[4], k4[4];
#pragma unroll
      for (int e = 0; e < 4; ++e) {
        float t = __sinf(y[e] + g[e]);
        k1[e] = t * t - y[e];
      }
#pragma unroll
      for (int e = 0; e < 4; ++e) {
        float yy = fmaf(h2, k1[e], y[e]);
        float t = __sinf(yy + g[e]);
        k2[e] = t * t - yy;
      }
#pragma unroll
      for (int e = 0; e < 4; ++e) {
        float yy = fmaf(h2, k2[e], y[e]);
        float t = __sinf(yy + g[e]);
        k3[e] = t * t - yy;
      }
#pragma unroll
      for (int e = 0; e < 4; ++e) {
        float yy = fmaf(hd, k3[e], y[e]);
        float t = __sinf(yy + g[e]);
        k4[e] = t * t - yy;
      }
#pragma unroll
      for (int e = 0; e < 4; ++e) {
        float ks = k1[e] + 2.0f * (k2[e] + k3[e]) + k4[e];
        y[e] = fmaf(h6, ks, y[e]);
      }
    }
    f32x4 o4;
    o4[0] = y[0]; o4[1] = y[1]; o4[2] = y[2]; o4[3] = y[3];
    __builtin_nontemporal_store(o4, &reinterpret_cast<f32x4*>(hid)[i]);
    ushort4v ob;
    ob.x = f32_to_bf16(y[0]);
    ob.y = f32_to_bf16(y[1]);
    ob.z = f32_to_bf16(y[2]);
    ob.w = f32_to_bf16(y[3]);
    reinterpret_cast<ushort4v*>(hb)[i] = ob;
  }
}

// GEMM1: specialized 2-phase, BK=64. Partials of x @ We^T. 128x128 tile,
// 4 waves (2x2), split-K=2 -> 512 blocks = 2/CU; 64 KB LDS dbuf still
// admits 2/CU (no occupancy cost; m132's BK regression was 3->2).
// 24 K-iterations (vs 48 at BK=32): halves barrier-drain count with the
// proven gemm1k BK=64 read pattern (row&7 swizzle, 0 conflicts measured).
// f32 partial at Cout + sk*BATCH*HID, coalesced cached store.
__global__ __launch_bounds__(256) void gemm1s(
    const unsigned short* __restrict__ A, const unsigned short* __restrict__ B,
    float* __restrict__ Cout) {
  constexpr int BM = 128, BN = 128, BK = 64;
  constexpr int Kstride = IN_DIM;    // 3072
  constexpr int Klen = Kstride / 2;  // 1536
  constexpr int ntT = Klen / BK;     // 24
  constexpr int nbn = HID / BN;      // 8
  constexpr int nbm = BATCH / BM;    // 32
  constexpr int tiles = nbm * nbn;   // 256

  __shared__ unsigned short As[2][BM * BK];
  __shared__ unsigned short Bs[2][BN * BK];

  const int tid = threadIdx.x;
  const int wave = tid >> 6;
  const int lane = tid & 63;
  const int wrow = wave >> 1, wcol = wave & 1;

  const int nwg = gridDim.x;  // 512
  const int swz = (blockIdx.x & 7) * (nwg >> 3) + (blockIdx.x >> 3);
  const int sk = swz / tiles;
  const int rem = swz % tiles;
  const int bn = rem % nbn;
  const int bm = rem / nbn;

  const unsigned short* Ablk = A + (size_t)bm * BM * Kstride + sk * Klen;
  const unsigned short* Bblk = B + (size_t)bn * BN * Kstride + sk * Klen;

  const int srow = tid >> 3;  // 0..31: row within a 32-row stage round
  const int sgl = tid & 7;    // logical 16B granule (8 per 64-col row)

  // 8 rounds: r=0..3 -> A rows {32r..32r+31}; r=4..7 -> B same.
  auto STAGE = [&](int buf, int k0) {
#pragma unroll
    for (int r = 0; r < 8; ++r) {
      const int rr = (r & 3) * 32 + srow;
      const int g = sgl ^ (rr & 7);  // inverse-swizzled global source
      if (r < 4)
        gload_lds16(Ablk + (size_t)rr * Kstride + k0 + g * 8,
                    (void*)&As[buf][(r & 3) * 2048 + tid * 8]);
      else
        gload_lds16(Bblk + (size_t)rr * Kstride + k0 + g * 8,
                    (void*)&Bs[buf][(r & 3) * 2048 + tid * 8]);
    }
  };

  const int fr = lane & 15;
  const int hi = lane >> 4;

  f32x4 acc[4][4] = {};

  STAGE(0, 0);
#pragma unroll 1
  for (int t = 0; t < ntT; ++t) {
    const int buf = t & 1;
    __syncthreads();  // compiler drains vmcnt/lgkm: tile t resident
    if (t + 1 < ntT) STAGE(buf ^ 1, (t + 1) * BK);

    short8 af[4][2], bfr[4][2];
#pragma unroll
    for (int m = 0; m < 4; ++m) {
      const int row = wrow * 64 + m * 16 + fr;
#pragma unroll
      for (int kk = 0; kk < 2; ++kk) {
        const int g = (kk * 4 + hi) ^ (row & 7);  // swizzled read granule
        af[m][kk] =
            *reinterpret_cast<const short8*>(&As[buf][row * BK + g * 8]);
      }
    }
#pragma unroll
    for (int n = 0; n < 4; ++n) {
      const int row = wcol * 64 + n * 16 + fr;
#pragma unroll
      for (int kk = 0; kk < 2; ++kk) {
        const int g = (kk * 4 + hi) ^ (row & 7);
        bfr[n][kk] =
            *reinterpret_cast<const short8*>(&Bs[buf][row * BK + g * 8]);
      }
    }
#pragma unroll
    for (int kk = 0; kk < 2; ++kk)
#pragma unroll
      for (int m = 0; m < 4; ++m)
#pragma unroll
        for (int n = 0; n < 4; ++n)
          acc[m][n] = __builtin_amdgcn_mfma_f32_16x16x32_bf16(
              af[m][kk], bfr[n][kk], acc[m][n], 0, 0, 0);
  }

  // epilogue: C/D layout col=lane&15, row=(lane>>4)*4+reg (m89-verified)
  const int rowbase = bm * BM + wrow * 64 + hi * 4;
  const int colbase = bn * BN + wcol * 64 + fr;
  float* Cblk = Cout + (size_t)sk * BATCH * HID;
#pragma unroll
  for (int n = 0; n < 4; ++n)
#pragma unroll
    for (int m = 0; m < 4; ++m)
#pragma unroll
      for (int r = 0; r < 4; ++r) {
        size_t idx = (size_t)(rowbase + m * 16 + r) * HID + (colbase + n * 16);
        Cblk[idx] = acc[m][n][r];
      }
}

// GEMM2 (R14 verbatim, measured 42.4us): specialized m97 2-phase, 128x128,
// BK=32, 4 waves, 768 blocks = 3/CU. bias + sigmoid, NT f32 store.
__global__ __launch_bounds__(256) void gemm2s(
    const unsigned short* __restrict__ A, const unsigned short* __restrict__ B,
    const float* __restrict__ bias, float* __restrict__ Cout) {
  constexpr int BM = 128, BN = 128, BK = 32;
  constexpr int Kstride = HID;      // 1024
  constexpr int ntT = Kstride / BK; // 32
  constexpr int nbn = IN_DIM / BN;  // 24
  constexpr int Nout = IN_DIM;

  __shared__ unsigned short As[2][BM * BK];
  __shared__ unsigned short Bs[2][BN * BK];

  const int tid = threadIdx.x;
  const int wave = tid >> 6;
  const int lane = tid & 63;
  const int wrow = wave >> 1, wcol = wave & 1;

  const int nwg = gridDim.x;  // 768
  const int swz = (blockIdx.x & 7) * (nwg >> 3) + (blockIdx.x >> 3);
  const int bn = swz % nbn;
  const int bm = swz / nbn;

  const unsigned short* Ablk = A + (size_t)bm * BM * Kstride;
  const unsigned short* Bblk = B + (size_t)bn * BN * Kstride;

  const int srow = tid >> 2;
  const int sgr = tid & 3;

  auto STAGE = [&](int buf, int k0) {
#pragma unroll
    for (int r = 0; r < 4; ++r) {
      const int rr = srow + (r & 1) * 64;
      const int g = sgr ^ swz4(rr);
      if (r < 2)
        gload_lds16(Ablk + (size_t)rr * Kstride + k0 + g * 8,
                    (void*)&As[buf][(r & 1) * 2048 + tid * 8]);
      else
        gload_lds16(Bblk + (size_t)rr * Kstride + k0 + g * 8,
                    (void*)&Bs[buf][(r & 1) * 2048 + tid * 8]);
    }
  };

  const int fr = lane & 15;
  const int hi = lane >> 4;

  f32x4 acc[4][4] = {};

  STAGE(0, 0);
#pragma unroll 1
  for (int t = 0; t < ntT; ++t) {
    const int buf = t & 1;
    __syncthreads();
    if (t + 1 < ntT) STAGE(buf ^ 1, (t + 1) * BK);

    short8 af[4], bfr[4];
#pragma unroll
    for (int m = 0; m < 4; ++m) {
      const int row = wrow * 64 + m * 16 + fr;
      const int g = hi ^ swz4(row);
      af[m] = *reinterpret_cast<const short8*>(&As[buf][row * BK + g * 8]);
    }
#pragma unroll
    for (int n = 0; n < 4; ++n) {
      const int row = wcol * 64 + n * 16 + fr;
      const int g = hi ^ swz4(row);
      bfr[n] = *reinterpret_cast<const short8*>(&Bs[buf][row * BK + g * 8]);
    }
#pragma unroll
    for (int m = 0; m < 4; ++m)
#pragma unroll
      for (int n = 0; n < 4; ++n)
        acc[m][n] = __builtin_amdgcn_mfma_f32_16x16x32_bf16(af[m], bfr[n],
                                                            acc[m][n], 0, 0, 0);
  }

  const int rowbase = bm * BM + wrow * 64 + hi * 4;
  const int colbase = bn * BN + wcol * 64 + fr;
#pragma unroll
  for (int n = 0; n < 4; ++n) {
    const float bv = bias[colbase + n * 16];
#pragma unroll
    for (int m = 0; m < 4; ++m)
#pragma unroll
      for (int r = 0; r < 4; ++r) {
        float v = acc[m][n][r] + bv;
        v = 1.0f / (1.0f + __expf(-v));
        size_t idx = (size_t)(rowbase + m * 16 + r) * Nout + (colbase + n * 16);
        __builtin_nontemporal_store(v, &Cout[idx]);
      }
  }
}

extern "C" void kernel_launch(void* const* d_in, const int* in_sizes, int n_in,
                              void* d_out, int out_size, void* d_ws,
                              size_t ws_size, hipStream_t stream) {
  const float* x = (const float*)d_in[0];
  const float* We = (const float*)d_in[1];
  const float* be = (const float*)d_in[2];
  const float* Wd = (const float*)d_in[3];
  const float* bd = (const float*)d_in[4];

  float* out = (float*)d_out;                 // [4096,3072]
  float* hid = out + (size_t)BATCH * IN_DIM;  // [4096,1024]
  // split-K=2 f32 partials (33.6MB) in the out region (50MB); GEMM2 last.
  float* part = out;

  unsigned short* xb = (unsigned short*)d_ws;          // bf16 x   [4096,3072]
  unsigned short* Web = xb + (size_t)BATCH * IN_DIM;   // bf16 We  [1024,3072]
  unsigned short* Wdb = Web + (size_t)HID * IN_DIM;    // bf16 Wd  [3072,1024]
  unsigned short* hb = Wdb + (size_t)IN_DIM * HID;     // bf16 hid [4096,1024]

  cvt3_kernel<<<2048, 256, 0, stream>>>(
      x, We, Wd, xb, Web, Wdb, BATCH * IN_DIM / 4, HID * IN_DIM / 4,
      IN_DIM * HID / 4);

  // GEMM1: specialized 2-phase BK=64, f32 partials of x @ We^T. split-K=2,
  // 512 blocks = 2/CU fully resident.
  gemm1s<<<512, 256, 0, stream>>>(xb, Web, part);

  // ODE: gamma = p0+p1+be, RK4 -> hid f32 (NT) + hb bf16
  ode_kernel<<<2048, 256, 0, stream>>>(part, part + (size_t)BATCH * HID, be,
                                       hid, hb, BATCH * HID / 4);

  // GEMM2: out = sigmoid(y @ Wd^T + bd). 768 blocks = 3/CU
  gemm2s<<<768, 256, 0, stream>>>(hb, Wdb, bd, out);
}

// Round 16
// 103.720 us; speedup vs baseline: 1.1660x; 1.0597x over previous
//
#include <hip/hip_runtime.h>
#include <hip/hip_bf16.h>

#define BATCH 4096
#define IN_DIM 3072
#define HID 1024
#define NSTEP 6

typedef __attribute__((ext_vector_type(8))) short short8;
typedef __attribute__((ext_vector_type(4))) float f32x4;
typedef __attribute__((ext_vector_type(4))) unsigned short ushort4v;

__device__ __forceinline__ void gload_lds16(const void* g, void* lds) {
  __builtin_amdgcn_global_load_lds(
      (const __attribute__((address_space(1))) void*)g,
      (__attribute__((address_space(3))) void*)lds, 16, 0, 0);
}

__device__ __forceinline__ unsigned short f32_to_bf16(float f) {
  unsigned int u = __builtin_bit_cast(unsigned int, f);
  unsigned int r = u + 0x7fffu + ((u >> 16) & 1u);
  return (unsigned short)(r >> 16);
}

// fused f32 -> bf16 conversion of x, We, Wd (one launch)
__global__ void cvt3_kernel(const float* __restrict__ a,
                            const float* __restrict__ b,
                            const float* __restrict__ c,
                            unsigned short* __restrict__ da,
                            unsigned short* __restrict__ db,
                            unsigned short* __restrict__ dc, int na, int nb,
                            int nc) {
  const int total = na + nb + nc;
  const int stride = gridDim.x * blockDim.x;
  for (int i = blockIdx.x * blockDim.x + threadIdx.x; i < total; i += stride) {
    const float* s;
    unsigned short* d;
    int j = i;
    if (j < na) {
      s = a; d = da;
    } else if (j < na + nb) {
      s = b; d = db; j -= na;
    } else {
      s = c; d = dc; j -= na + nb;
    }
    const float4 v = reinterpret_cast<const float4*>(s)[j];
    ushort4v o;
    o.x = f32_to_bf16(v.x);
    o.y = f32_to_bf16(v.y);
    o.z = f32_to_bf16(v.z);
    o.w = f32_to_bf16(v.w);
    reinterpret_cast<ushort4v*>(d)[j] = o;
  }
}

// Split-K2 reduce (p0+p1+bias) + RK4 nmODE. Writes y f32 (NT) + bf16.
__global__ __launch_bounds__(256) void ode_kernel(
    const float* __restrict__ p0, const float* __restrict__ p1,
    const float* __restrict__ be, float* __restrict__ hid,
    unsigned short* __restrict__ hb, int n4) {
  const float dt = 1.0f / (float)NSTEP;
  const float h2 = 0.5f * dt, hd = dt, h6 = dt / 6.0f;
  int stride = gridDim.x * blockDim.x;
  for (int i = blockIdx.x * blockDim.x + threadIdx.x; i < n4; i += stride) {
    const float4 a4 = reinterpret_cast<const float4*>(p0)[i];
    const float4 b4 = reinterpret_cast<const float4*>(p1)[i];
    const float4 e4 = reinterpret_cast<const float4*>(be)[i & (HID / 4 - 1)];
    float g[4] = {a4.x + b4.x + e4.x, a4.y + b4.y + e4.y,
                  a4.z + b4.z + e4.z, a4.w + b4.w + e4.w};
    float y[4] = {0.0f, 0.0f, 0.0f, 0.0f};
#pragma unroll 1
    for (int s = 0; s < NSTEP; ++s) {
      float k1[4], k2[4], k3[4], k4[4];
#pragma unroll
      for (int e = 0; e < 4; ++e) {
        float t = __sinf(y[e] + g[e]);
        k1[e] = t * t - y[e];
      }
#pragma unroll
      for (int e = 0; e < 4; ++e) {
        float yy = fmaf(h2, k1[e], y[e]);
        float t = __sinf(yy + g[e]);
        k2[e] = t * t - yy;
      }
#pragma unroll
      for (int e = 0; e < 4; ++e) {
        float yy = fmaf(h2, k2[e], y[e]);
        float t = __sinf(yy + g[e]);
        k3[e] = t * t - yy;
      }
#pragma unroll
      for (int e = 0; e < 4; ++e) {
        float yy = fmaf(hd, k3[e], y[e]);
        float t = __sinf(yy + g[e]);
        k4[e] = t * t - yy;
      }
#pragma unroll
      for (int e = 0; e < 4; ++e) {
        float ks = k1[e] + 2.0f * (k2[e] + k3[e]) + k4[e];
        y[e] = fmaf(h6, ks, y[e]);
      }
    }
    f32x4 o4;
    o4[0] = y[0]; o4[1] = y[1]; o4[2] = y[2]; o4[3] = y[3];
    __builtin_nontemporal_store(o4, &reinterpret_cast<f32x4*>(hid)[i]);
    ushort4v ob;
    ob.x = f32_to_bf16(y[0]);
    ob.y = f32_to_bf16(y[1]);
    ob.z = f32_to_bf16(y[2]);
    ob.w = f32_to_bf16(y[3]);
    reinterpret_cast<ushort4v*>(hb)[i] = ob;
  }
}

// GEMM1 (R15 verbatim, measured ~35us): specialized 2-phase, BK=64,
// 128x128 tile, 4 waves, split-K=2 -> 512 blocks = 2/CU. Row&7 swizzle.
// f32 partial at Cout + sk*BATCH*HID, coalesced cached store.
__global__ __launch_bounds__(256) void gemm1s(
    const unsigned short* __restrict__ A, const unsigned short* __restrict__ B,
    float* __restrict__ Cout) {
  constexpr int BM = 128, BN = 128, BK = 64;
  constexpr int Kstride = IN_DIM;    // 3072
  constexpr int Klen = Kstride / 2;  // 1536
  constexpr int ntT = Klen / BK;     // 24
  constexpr int nbn = HID / BN;      // 8
  constexpr int nbm = BATCH / BM;    // 32
  constexpr int tiles = nbm * nbn;   // 256

  __shared__ unsigned short As[2][BM * BK];
  __shared__ unsigned short Bs[2][BN * BK];

  const int tid = threadIdx.x;
  const int wave = tid >> 6;
  const int lane = tid & 63;
  const int wrow = wave >> 1, wcol = wave & 1;

  const int nwg = gridDim.x;  // 512
  const int swz = (blockIdx.x & 7) * (nwg >> 3) + (blockIdx.x >> 3);
  const int sk = swz / tiles;
  const int rem = swz % tiles;
  const int bn = rem % nbn;
  const int bm = rem / nbn;

  const unsigned short* Ablk = A + (size_t)bm * BM * Kstride + sk * Klen;
  const unsigned short* Bblk = B + (size_t)bn * BN * Kstride + sk * Klen;

  const int srow = tid >> 3;  // 0..31: row within a 32-row stage round
  const int sgl = tid & 7;    // logical 16B granule (8 per 64-col row)

  auto STAGE = [&](int buf, int k0) {
#pragma unroll
    for (int r = 0; r < 8; ++r) {
      const int rr = (r & 3) * 32 + srow;
      const int g = sgl ^ (rr & 7);  // inverse-swizzled global source
      if (r < 4)
        gload_lds16(Ablk + (size_t)rr * Kstride + k0 + g * 8,
                    (void*)&As[buf][(r & 3) * 2048 + tid * 8]);
      else
        gload_lds16(Bblk + (size_t)rr * Kstride + k0 + g * 8,
                    (void*)&Bs[buf][(r & 3) * 2048 + tid * 8]);
    }
  };

  const int fr = lane & 15;
  const int hi = lane >> 4;

  f32x4 acc[4][4] = {};

  STAGE(0, 0);
#pragma unroll 1
  for (int t = 0; t < ntT; ++t) {
    const int buf = t & 1;
    __syncthreads();
    if (t + 1 < ntT) STAGE(buf ^ 1, (t + 1) * BK);

    short8 af[4][2], bfr[4][2];
#pragma unroll
    for (int m = 0; m < 4; ++m) {
      const int row = wrow * 64 + m * 16 + fr;
#pragma unroll
      for (int kk = 0; kk < 2; ++kk) {
        const int g = (kk * 4 + hi) ^ (row & 7);
        af[m][kk] =
            *reinterpret_cast<const short8*>(&As[buf][row * BK + g * 8]);
      }
    }
#pragma unroll
    for (int n = 0; n < 4; ++n) {
      const int row = wcol * 64 + n * 16 + fr;
#pragma unroll
      for (int kk = 0; kk < 2; ++kk) {
        const int g = (kk * 4 + hi) ^ (row & 7);
        bfr[n][kk] =
            *reinterpret_cast<const short8*>(&Bs[buf][row * BK + g * 8]);
      }
    }
#pragma unroll
    for (int kk = 0; kk < 2; ++kk)
#pragma unroll
      for (int m = 0; m < 4; ++m)
#pragma unroll
        for (int n = 0; n < 4; ++n)
          acc[m][n] = __builtin_amdgcn_mfma_f32_16x16x32_bf16(
              af[m][kk], bfr[n][kk], acc[m][n], 0, 0, 0);
  }

  const int rowbase = bm * BM + wrow * 64 + hi * 4;
  const int colbase = bn * BN + wcol * 64 + fr;
  float* Cblk = Cout + (size_t)sk * BATCH * HID;
#pragma unroll
  for (int n = 0; n < 4; ++n)
#pragma unroll
    for (int m = 0; m < 4; ++m)
#pragma unroll
      for (int r = 0; r < 4; ++r) {
        size_t idx = (size_t)(rowbase + m * 16 + r) * HID + (colbase + n * 16);
        Cblk[idx] = acc[m][n][r];
      }
}

// GEMM2: BK=64 version (the R15 lever applied). 128x192 tile, 4 waves
// (2x2, per-wave 64x96, acc 4x6), grid 32x16 = 512 = exactly 2/CU uniform.
// LDS 80 KB/block -> 2 blocks = 160 KB = full CU LDS. 16 K-iterations
// (vs 32 at BK=32): halves barrier-drain count; 48 MFMA : 20 ds_read per
// iter. Proven row&7 swizzle (0 conflicts at BK=64). bias+sigmoid NT store.
__global__ __launch_bounds__(256) void gemm2s(
    const unsigned short* __restrict__ A, const unsigned short* __restrict__ B,
    const float* __restrict__ bias, float* __restrict__ Cout) {
  constexpr int BM = 128, BN = 192, BK = 64;
  constexpr int Kstride = HID;       // 1024
  constexpr int ntT = Kstride / BK;  // 16
  constexpr int nbn = IN_DIM / BN;   // 16
  constexpr int Nout = IN_DIM;

  __shared__ unsigned short As[2][BM * BK];  // 32 KB
  __shared__ unsigned short Bs[2][BN * BK];  // 48 KB

  const int tid = threadIdx.x;
  const int wave = tid >> 6;
  const int lane = tid & 63;
  const int wrow = wave >> 1, wcol = wave & 1;

  const int nwg = gridDim.x;  // 512
  const int swz = (blockIdx.x & 7) * (nwg >> 3) + (blockIdx.x >> 3);
  const int bn = swz % nbn;
  const int bm = swz / nbn;

  const unsigned short* Ablk = A + (size_t)bm * BM * Kstride;
  const unsigned short* Bblk = B + (size_t)bn * BN * Kstride;

  const int srow = tid >> 3;  // 0..31: row within a 32-row stage round
  const int sgl = tid & 7;

  // 10 rounds: r=0..3 -> A rows {32r..}, r=4..9 -> B rows {32(r-4)..}
  auto STAGE = [&](int buf, int k0) {
#pragma unroll
    for (int r = 0; r < 10; ++r) {
      if (r < 4) {
        const int rr = r * 32 + srow;
        const int g = sgl ^ (rr & 7);  // inverse-swizzled global source
        gload_lds16(Ablk + (size_t)rr * Kstride + k0 + g * 8,
                    (void*)&As[buf][r * 2048 + tid * 8]);
      } else {
        const int rr = (r - 4) * 32 + srow;
        const int g = sgl ^ (rr & 7);
        gload_lds16(Bblk + (size_t)rr * Kstride + k0 + g * 8,
                    (void*)&Bs[buf][(r - 4) * 2048 + tid * 8]);
      }
    }
  };

  const int fr = lane & 15;
  const int hi = lane >> 4;

  f32x4 acc[4][6] = {};

  STAGE(0, 0);
#pragma unroll 1
  for (int t = 0; t < ntT; ++t) {
    const int buf = t & 1;
    __syncthreads();  // compiler drains vmcnt/lgkm: tile t resident
    if (t + 1 < ntT) STAGE(buf ^ 1, (t + 1) * BK);

    short8 af[4][2], bfr[6][2];
#pragma unroll
    for (int m = 0; m < 4; ++m) {
      const int row = wrow * 64 + m * 16 + fr;
#pragma unroll
      for (int kk = 0; kk < 2; ++kk) {
        const int g = (kk * 4 + hi) ^ (row & 7);  // swizzled read granule
        af[m][kk] =
            *reinterpret_cast<const short8*>(&As[buf][row * BK + g * 8]);
      }
    }
#pragma unroll
    for (int n = 0; n < 6; ++n) {
      const int row = wcol * 96 + n * 16 + fr;
#pragma unroll
      for (int kk = 0; kk < 2; ++kk) {
        const int g = (kk * 4 + hi) ^ (row & 7);
        bfr[n][kk] =
            *reinterpret_cast<const short8*>(&Bs[buf][row * BK + g * 8]);
      }
    }
#pragma unroll
    for (int kk = 0; kk < 2; ++kk)
#pragma unroll
      for (int m = 0; m < 4; ++m)
#pragma unroll
        for (int n = 0; n < 6; ++n)
          acc[m][n] = __builtin_amdgcn_mfma_f32_16x16x32_bf16(
              af[m][kk], bfr[n][kk], acc[m][n], 0, 0, 0);
  }

  // epilogue: C/D layout col=lane&15, row=(lane>>4)*4+reg (m89-verified)
  const int rowbase = bm * BM + wrow * 64 + hi * 4;
  const int colbase = bn * BN + wcol * 96 + fr;
#pragma unroll
  for (int n = 0; n < 6; ++n) {
    const float bv = bias[colbase + n * 16];
#pragma unroll
    for (int m = 0; m < 4; ++m)
#pragma unroll
      for (int r = 0; r < 4; ++r) {
        float v = acc[m][n][r] + bv;
        v = 1.0f / (1.0f + __expf(-v));
        size_t idx = (size_t)(rowbase + m * 16 + r) * Nout + (colbase + n * 16);
        __builtin_nontemporal_store(v, &Cout[idx]);
      }
  }
}

extern "C" void kernel_launch(void* const* d_in, const int* in_sizes, int n_in,
                              void* d_out, int out_size, void* d_ws,
                              size_t ws_size, hipStream_t stream) {
  const float* x = (const float*)d_in[0];
  const float* We = (const float*)d_in[1];
  const float* be = (const float*)d_in[2];
  const float* Wd = (const float*)d_in[3];
  const float* bd = (const float*)d_in[4];

  float* out = (float*)d_out;                 // [4096,3072]
  float* hid = out + (size_t)BATCH * IN_DIM;  // [4096,1024]
  // split-K=2 f32 partials (33.6MB) in the out region (50MB); GEMM2 last.
  float* part = out;

  unsigned short* xb = (unsigned short*)d_ws;          // bf16 x   [4096,3072]
  unsigned short* Web = xb + (size_t)BATCH * IN_DIM;   // bf16 We  [1024,3072]
  unsigned short* Wdb = Web + (size_t)HID * IN_DIM;    // bf16 Wd  [3072,1024]
  unsigned short* hb = Wdb + (size_t)IN_DIM * HID;     // bf16 hid [4096,1024]

  cvt3_kernel<<<2048, 256, 0, stream>>>(
      x, We, Wd, xb, Web, Wdb, BATCH * IN_DIM / 4, HID * IN_DIM / 4,
      IN_DIM * HID / 4);

  // GEMM1: specialized 2-phase BK=64, f32 partials of x @ We^T. split-K=2,
  // 512 blocks = 2/CU fully resident.
  gemm1s<<<512, 256, 0, stream>>>(xb, Web, part);

  // ODE: gamma = p0+p1+be, RK4 -> hid f32 (NT) + hb bf16
  ode_kernel<<<2048, 256, 0, stream>>>(part, part + (size_t)BATCH * HID, be,
                                       hid, hb, BATCH * HID / 4);

  // GEMM2: out = sigmoid(y @ Wd^T + bd). 128x192, BK=64 -> 512 blocks = 2/CU
  gemm2s<<<512, 256, 0, stream>>>(hb, Wdb, bd, out);
}